// Round 1
// baseline (546.526 us; speedup 1.0000x reference)
//
#include <hip/hip_runtime.h>
#include <cstdint>
#include <cstddef>

// Problem constants
#define N_TOK 4096     // B*T tokens
#define DM    1024     // d_model
#define DH    2048     // d_hidden
#define NE    8        // experts
#define NSLOT 8192     // total routed slots = N_TOK * top_k

typedef short bf16x8_t __attribute__((ext_vector_type(8)));  // 8 bf16 (4 VGPRs)
typedef float f32x4    __attribute__((ext_vector_type(4)));

__device__ __forceinline__ unsigned short f2bf(float f) {
  union { float f; unsigned int u; } v; v.f = f;
  unsigned int u = v.u;
  u += 0x7fffu + ((u >> 16) & 1u);   // RNE
  return (unsigned short)(u >> 16);
}

#define GLD16(gp, lp)                                                          \
  __builtin_amdgcn_global_load_lds(                                            \
      (const __attribute__((address_space(1))) void*)(gp),                     \
      (__attribute__((address_space(3))) void*)(lp), 16, 0, 0)

// ---------------------------------------------------------------------------
// Transpose + fp32->bf16 convert: src [R][C] fp32 -> dst [C][R] bf16 (per expert)
// ---------------------------------------------------------------------------
__global__ __launch_bounds__(256) void k_transpose_bf16(
    const float* __restrict__ src, unsigned short* __restrict__ dst,
    int R, int C, long srcEStride, long dstEStride, int dstRowOff) {
  const int e = blockIdx.z;
  const float* s = src + (size_t)e * srcEStride;
  unsigned short* d = dst + (size_t)e * dstEStride;
  const int c0 = blockIdx.x * 32, r0 = blockIdx.y * 32;
  __shared__ float tile[32][33];
  const int tx = threadIdx.x & 31, ty = threadIdx.x >> 5;  // ty in 0..7
#pragma unroll
  for (int j = 0; j < 4; j++) {
    const int r = ty + j * 8;
    tile[r][tx] = s[(size_t)(r0 + r) * C + c0 + tx];
  }
  __syncthreads();
#pragma unroll
  for (int j = 0; j < 4; j++) {
    const int r = ty + j * 8;  // output row within tile (= source col)
    d[(size_t)(dstRowOff + c0 + r) * R + r0 + tx] = f2bf(tile[tx][r]);
  }
}

// ---------------------------------------------------------------------------
// Router: fp32 logits, top-2, softmax, atomic per-expert slot assignment.
// One wave per token.
// ---------------------------------------------------------------------------
__global__ __launch_bounds__(256) void k_router(
    const float* __restrict__ x, const float* __restrict__ rw,
    const float* __restrict__ rb, int* __restrict__ counts,
    int* __restrict__ meta_e, int* __restrict__ meta_idx,
    float* __restrict__ meta_p) {
  const int wv = threadIdx.x >> 6;
  const int l  = threadIdx.x & 63;
  const int tk = blockIdx.x * 4 + wv;
  const float* xr = x + (size_t)tk * DM;

  float acc[NE];
#pragma unroll
  for (int e = 0; e < NE; e++) acc[e] = 0.f;
#pragma unroll 4
  for (int i = 0; i < DM / 64; i++) {
    const float xv = xr[i * 64 + l];
#pragma unroll
    for (int e = 0; e < NE; e++) acc[e] += xv * rw[e * DM + i * 64 + l];
  }
#pragma unroll
  for (int off = 32; off > 0; off >>= 1) {
#pragma unroll
    for (int e = 0; e < NE; e++) acc[e] += __shfl_xor(acc[e], off);
  }
#pragma unroll
  for (int e = 0; e < NE; e++) acc[e] += rb[e];

  // top-2, ascending scan with strict > (ties -> lower index, matches top_k)
  float v0 = -1e30f; int e0 = 0;
#pragma unroll
  for (int e = 0; e < NE; e++) { if (acc[e] > v0) { v0 = acc[e]; e0 = e; } }
  float v1 = -1e30f; int e1 = 0;
#pragma unroll
  for (int e = 0; e < NE; e++) { if (e != e0 && acc[e] > v1) { v1 = acc[e]; e1 = e; } }
  const float p0 = 1.0f / (1.0f + __expf(v1 - v0));
  const float p1 = 1.0f - p0;

  if (l == 0) {
    const int i0 = atomicAdd(&counts[e0], 1);
    const int i1 = atomicAdd(&counts[e1], 1);
    meta_e[tk * 2 + 0] = e0;  meta_e[tk * 2 + 1] = e1;
    meta_idx[tk * 2 + 0] = i0; meta_idx[tk * 2 + 1] = i1;
    meta_p[tk * 2 + 0] = p0;  meta_p[tk * 2 + 1] = p1;
  }
}

__global__ void k_prefix(const int* __restrict__ counts, int* __restrict__ offsets) {
  if (threadIdx.x == 0) {
    int s = 0;
#pragma unroll
    for (int e = 0; e < NE; e++) { offsets[e] = s; s += counts[e]; }
  }
}

// ---------------------------------------------------------------------------
// Gather: pack token rows (fp32 -> bf16) into expert-contiguous Xg [NSLOT][DM]
// One block per (token, k) pair.
// ---------------------------------------------------------------------------
__global__ __launch_bounds__(256) void k_gather(
    const float* __restrict__ x, const int* __restrict__ meta_e,
    const int* __restrict__ meta_idx, const float* __restrict__ meta_p,
    const int* __restrict__ offsets, unsigned short* __restrict__ Xg,
    int* __restrict__ tok_of_slot, float* __restrict__ wt_of_slot) {
  const int s = blockIdx.x;      // token*2 + k
  const int tk = s >> 1;
  const int e = meta_e[s];
  const int gslot = offsets[e] + meta_idx[s];
  if (threadIdx.x == 0) {
    tok_of_slot[gslot] = tk;
    wt_of_slot[gslot] = meta_p[s];
  }
  const float4 v = ((const float4*)(x + (size_t)tk * DM))[threadIdx.x];
  ushort4 o;
  o.x = f2bf(v.x); o.y = f2bf(v.y); o.z = f2bf(v.z); o.w = f2bf(v.w);
  *(ushort4*)(Xg + (size_t)gslot * DM + threadIdx.x * 4) = o;
}

// ---------------------------------------------------------------------------
// GEMM1 fused SwiGLU: per expert, A = Xg rows [cnt][1024] bf16,
// Bw/Bv = transposed weights [n][k] bf16; epilogue g = a * silu(b) -> G bf16.
// 128x128 output tile per block (h-dim), dual accumulators for W and V halves.
// ---------------------------------------------------------------------------
__global__ __launch_bounds__(256, 2) void k_gemm1(
    const unsigned short* __restrict__ Xg, const unsigned short* __restrict__ B1t,
    unsigned short* __restrict__ G, const int* __restrict__ counts,
    const int* __restrict__ offsets) {
  const int e = blockIdx.z;
  const int mt = blockIdx.y;
  const int cnt = counts[e];
  if (mt * 128 >= cnt) return;
  const int h0 = blockIdx.x * 128;
  const int off = offsets[e];
  const int row_base = off + mt * 128;

  __shared__ unsigned short As[128 * 32];
  __shared__ unsigned short Ws[128 * 32];
  __shared__ unsigned short Vs[128 * 32];

  const int t = threadIdx.x;
  const int l = t & 63;
  const int w = t >> 6;
  const int wm = (w >> 1) * 64;
  const int wn = (w & 1) * 64;
  const int lr = l & 15;
  const int kq = (l >> 4) * 8;

  const unsigned short* Bw = B1t + ((size_t)e * 4096 + h0) * DM;
  const unsigned short* Bv = Bw + (size_t)DH * DM;

  const int c0 = t, c1 = t + 256;
  const int ar0 = c0 >> 2, ak0 = (c0 & 3) * 8;
  const int ar1 = c1 >> 2, ak1 = (c1 & 3) * 8;
  const int arow0 = min(row_base + ar0, NSLOT - 1);  // clamp: no OOB reads
  const int arow1 = min(row_base + ar1, NSLOT - 1);

  f32x4 acc_a[4][4], acc_b[4][4];
  const f32x4 z4 = {0.f, 0.f, 0.f, 0.f};
#pragma unroll
  for (int i = 0; i < 4; i++)
#pragma unroll
    for (int j = 0; j < 4; j++) { acc_a[i][j] = z4; acc_b[i][j] = z4; }

  for (int k0 = 0; k0 < DM; k0 += 32) {
    __syncthreads();
    GLD16(Xg + (size_t)arow0 * DM + k0 + ak0, As + c0 * 8);
    GLD16(Xg + (size_t)arow1 * DM + k0 + ak1, As + c1 * 8);
    GLD16(Bw + (size_t)ar0 * DM + k0 + ak0, Ws + c0 * 8);
    GLD16(Bw + (size_t)ar1 * DM + k0 + ak1, Ws + c1 * 8);
    GLD16(Bv + (size_t)ar0 * DM + k0 + ak0, Vs + c0 * 8);
    GLD16(Bv + (size_t)ar1 * DM + k0 + ak1, Vs + c1 * 8);
    __syncthreads();

    bf16x8_t af[4], wf[4], vf[4];
#pragma unroll
    for (int mi = 0; mi < 4; mi++)
      af[mi] = *(const bf16x8_t*)&As[(wm + mi * 16 + lr) * 32 + kq];
#pragma unroll
    for (int ni = 0; ni < 4; ni++) {
      wf[ni] = *(const bf16x8_t*)&Ws[(wn + ni * 16 + lr) * 32 + kq];
      vf[ni] = *(const bf16x8_t*)&Vs[(wn + ni * 16 + lr) * 32 + kq];
    }
#pragma unroll
    for (int mi = 0; mi < 4; mi++)
#pragma unroll
      for (int ni = 0; ni < 4; ni++) {
        acc_a[mi][ni] = __builtin_amdgcn_mfma_f32_16x16x32_bf16(af[mi], wf[ni], acc_a[mi][ni], 0, 0, 0);
        acc_b[mi][ni] = __builtin_amdgcn_mfma_f32_16x16x32_bf16(af[mi], vf[ni], acc_b[mi][ni], 0, 0, 0);
      }
  }

  const int q4 = (l >> 4) * 4;
#pragma unroll
  for (int mi = 0; mi < 4; mi++) {
#pragma unroll
    for (int r = 0; r < 4; r++) {
      const int mloc = mt * 128 + wm + mi * 16 + q4 + r;
      if (mloc >= cnt) continue;
      unsigned short* grow = G + (size_t)(off + mloc) * DH;
#pragma unroll
      for (int ni = 0; ni < 4; ni++) {
        const int h = h0 + wn + ni * 16 + lr;
        const float a = acc_a[mi][ni][r];
        const float b = acc_b[mi][ni][r];
        const float s = b / (1.0f + __expf(-b));  // silu(b)
        grow[h] = f2bf(a * s);
      }
    }
  }
}

// ---------------------------------------------------------------------------
// GEMM2: y = G @ W_out^T (B2t is [n=1024][k=2048] bf16 per expert),
// epilogue: weighted fp32 atomicAdd scatter to out[token].
// ---------------------------------------------------------------------------
__global__ __launch_bounds__(256, 2) void k_gemm2(
    const unsigned short* __restrict__ G, const unsigned short* __restrict__ B2t,
    float* __restrict__ out, const int* __restrict__ counts,
    const int* __restrict__ offsets, const int* __restrict__ tok_of_slot,
    const float* __restrict__ wt_of_slot) {
  const int e = blockIdx.z;
  const int mt = blockIdx.y;
  const int cnt = counts[e];
  if (mt * 128 >= cnt) return;
  const int n0 = blockIdx.x * 128;
  const int off = offsets[e];
  const int row_base = off + mt * 128;

  __shared__ unsigned short As[128 * 32];
  __shared__ unsigned short Bs[128 * 32];

  const int t = threadIdx.x;
  const int l = t & 63;
  const int w = t >> 6;
  const int wm = (w >> 1) * 64;
  const int wn = (w & 1) * 64;
  const int lr = l & 15;
  const int kq = (l >> 4) * 8;

  const unsigned short* Bp = B2t + ((size_t)e * DM + n0) * DH;

  const int c0 = t, c1 = t + 256;
  const int ar0 = c0 >> 2, ak0 = (c0 & 3) * 8;
  const int ar1 = c1 >> 2, ak1 = (c1 & 3) * 8;
  const int arow0 = min(row_base + ar0, NSLOT - 1);
  const int arow1 = min(row_base + ar1, NSLOT - 1);

  f32x4 acc[4][4];
  const f32x4 z4 = {0.f, 0.f, 0.f, 0.f};
#pragma unroll
  for (int i = 0; i < 4; i++)
#pragma unroll
    for (int j = 0; j < 4; j++) acc[i][j] = z4;

  for (int k0 = 0; k0 < DH; k0 += 32) {
    __syncthreads();
    GLD16(G + (size_t)arow0 * DH + k0 + ak0, As + c0 * 8);
    GLD16(G + (size_t)arow1 * DH + k0 + ak1, As + c1 * 8);
    GLD16(Bp + (size_t)ar0 * DH + k0 + ak0, Bs + c0 * 8);
    GLD16(Bp + (size_t)ar1 * DH + k0 + ak1, Bs + c1 * 8);
    __syncthreads();

    bf16x8_t af[4], bf[4];
#pragma unroll
    for (int mi = 0; mi < 4; mi++)
      af[mi] = *(const bf16x8_t*)&As[(wm + mi * 16 + lr) * 32 + kq];
#pragma unroll
    for (int ni = 0; ni < 4; ni++)
      bf[ni] = *(const bf16x8_t*)&Bs[(wn + ni * 16 + lr) * 32 + kq];
#pragma unroll
    for (int mi = 0; mi < 4; mi++)
#pragma unroll
      for (int ni = 0; ni < 4; ni++)
        acc[mi][ni] = __builtin_amdgcn_mfma_f32_16x16x32_bf16(af[mi], bf[ni], acc[mi][ni], 0, 0, 0);
  }

  const int q4 = (l >> 4) * 4;
#pragma unroll
  for (int mi = 0; mi < 4; mi++) {
#pragma unroll
    for (int r = 0; r < 4; r++) {
      const int mloc = mt * 128 + wm + mi * 16 + q4 + r;
      if (mloc >= cnt) continue;
      const int gs = off + mloc;
      const int tok = tok_of_slot[gs];
      const float wt = wt_of_slot[gs];
      float* orow = out + (size_t)tok * DM;
#pragma unroll
      for (int ni = 0; ni < 4; ni++) {
        const int n = n0 + wn + ni * 16 + lr;
        atomicAdd(&orow[n], acc[mi][ni][r] * wt);
      }
    }
  }
}

// ---------------------------------------------------------------------------
extern "C" void kernel_launch(void* const* d_in, const int* in_sizes, int n_in,
                              void* d_out, int out_size, void* d_ws, size_t ws_size,
                              hipStream_t stream) {
  const float* x    = (const float*)d_in[0];  // [2,2048,1024]
  const float* rw   = (const float*)d_in[1];  // [8,1024]
  const float* rb   = (const float*)d_in[2];  // [8]
  const float* W    = (const float*)d_in[3];  // [8,1024,2048]
  const float* V    = (const float*)d_in[4];  // [8,1024,2048]
  const float* Wout = (const float*)d_in[5];  // [8,2048,1024]
  float* out = (float*)d_out;

  // workspace carve-up (~151 MB)
  char* p = (char*)d_ws;
  unsigned short* B1t = (unsigned short*)p; p += (size_t)NE * 4096 * DM * 2;   // 64 MB [e][n=4096][k=1024]
  unsigned short* B2t = (unsigned short*)p; p += (size_t)NE * DM * DH * 2;     // 32 MB [e][n=1024][k=2048]
  unsigned short* Xg  = (unsigned short*)p; p += (size_t)NSLOT * DM * 2;       // 16 MB
  unsigned short* G   = (unsigned short*)p; p += (size_t)NSLOT * DH * 2;       // 32 MB
  int*   counts      = (int*)p;   p += 256;
  int*   offsets     = (int*)p;   p += 256;
  int*   meta_e      = (int*)p;   p += (size_t)N_TOK * 2 * 4;
  int*   meta_idx    = (int*)p;   p += (size_t)N_TOK * 2 * 4;
  float* meta_p      = (float*)p; p += (size_t)N_TOK * 2 * 4;
  int*   tok_of_slot = (int*)p;   p += (size_t)NSLOT * 4;
  float* wt_of_slot  = (float*)p; p += (size_t)NSLOT * 4;

  hipMemsetAsync(counts, 0, 256, stream);
  hipMemsetAsync(out, 0, (size_t)out_size * sizeof(float), stream);

  // weight transpose+convert: fp32 [k][n] -> bf16 [n][k]
  k_transpose_bf16<<<dim3(DH / 32, DM / 32, NE), 256, 0, stream>>>(
      W, B1t, DM, DH, (long)DM * DH, (long)4096 * DM, 0);
  k_transpose_bf16<<<dim3(DH / 32, DM / 32, NE), 256, 0, stream>>>(
      V, B1t, DM, DH, (long)DM * DH, (long)4096 * DM, DH);
  k_transpose_bf16<<<dim3(DM / 32, DH / 32, NE), 256, 0, stream>>>(
      Wout, B2t, DH, DM, (long)DH * DM, (long)DM * DH, 0);

  k_router<<<N_TOK / 4, 256, 0, stream>>>(x, rw, rb, counts, meta_e, meta_idx, meta_p);
  k_prefix<<<1, 64, 0, stream>>>(counts, offsets);
  k_gather<<<NSLOT, 256, 0, stream>>>(x, meta_e, meta_idx, meta_p, offsets, Xg,
                                      tok_of_slot, wt_of_slot);

  // GEMM1: grid (h-tiles=16, worst-case m-tiles=32, experts=8); early exit on counts
  k_gemm1<<<dim3(DH / 128, NSLOT / 128, NE), 256, 0, stream>>>(Xg, B1t, G, counts, offsets);
  // GEMM2: grid (n-tiles=8, m-tiles=32, experts=8)
  k_gemm2<<<dim3(DM / 128, NSLOT / 128, NE), 256, 0, stream>>>(G, B2t, out, counts, offsets,
                                                               tok_of_slot, wt_of_slot);
}

// Round 3
// 532.917 us; speedup vs baseline: 1.0255x; 1.0255x over previous
//
#include <hip/hip_runtime.h>
#include <cstdint>
#include <cstddef>

// Problem constants
#define N_TOK 4096     // B*T tokens
#define DM    1024     // d_model
#define DH    2048     // d_hidden
#define NE    8        // experts
#define NSLOT 8192     // total routed slots = N_TOK * top_k

typedef short bf16x8_t __attribute__((ext_vector_type(8)));  // 8 bf16 (4 VGPRs)
typedef float f32x4    __attribute__((ext_vector_type(4)));
typedef unsigned short u16x8 __attribute__((ext_vector_type(8)));

__device__ __forceinline__ unsigned short f2bf(float f) {
  union { float f; unsigned int u; } v; v.f = f;
  unsigned int u = v.u;
  u += 0x7fffu + ((u >> 16) & 1u);   // RNE
  return (unsigned short)(u >> 16);
}

#define GLD16(gp, lp)                                                          \
  __builtin_amdgcn_global_load_lds(                                            \
      (const __attribute__((address_space(1))) void*)(gp),                     \
      (__attribute__((address_space(3))) void*)(lp), 16, 0, 0)

// ---------------------------------------------------------------------------
// Transpose + fp32->bf16: src [R][C] fp32 -> dst [C][R] bf16, per expert.
// 64x64 tiles, float4 reads, ushort8 (16B) writes. grid.z selects expert and
// (optionally) a second source tensor placed at row offset rowOff1.
// FIX vs R2: write phase reads tile[r8+i][c] (was tile[c][r8+i] — transposed
// LDS indexing produced garbage weights). Bank check: lanes hit 32 banks
// 2-way -> conflict-free.
// ---------------------------------------------------------------------------
__global__ __launch_bounds__(256) void k_transpose_bf16(
    const float* __restrict__ src0, const float* __restrict__ src1,
    unsigned short* __restrict__ dst, int R, int C,
    long srcEStride, long dstEStride, int rowOff1) {
  const int z = blockIdx.z;
  const int e = z & 7;
  const bool second = z >= 8;
  const float* s = (second ? src1 : src0) + (size_t)e * srcEStride;
  unsigned short* d = dst + (size_t)e * dstEStride + (size_t)(second ? rowOff1 : 0) * R;
  const int c0 = blockIdx.x * 64, r0 = blockIdx.y * 64;
  __shared__ float tile[64][65];
  const int t = threadIdx.x;
  {
    const int cc = (t & 15) * 4;
#pragma unroll
    for (int j = 0; j < 4; j++) {
      const int r = (t >> 4) + j * 16;
      const float4 v = *(const float4*)(s + (size_t)(r0 + r) * C + c0 + cc);
      tile[r][cc + 0] = v.x; tile[r][cc + 1] = v.y;
      tile[r][cc + 2] = v.z; tile[r][cc + 3] = v.w;
    }
  }
  __syncthreads();
  {
    const int r8 = (t & 7) * 8;
#pragma unroll
    for (int j = 0; j < 2; j++) {
      const int c = (t >> 3) + j * 32;
      u16x8 o;
#pragma unroll
      for (int i = 0; i < 8; i++) o[i] = f2bf(tile[r8 + i][c]);
      *(u16x8*)(d + (size_t)(c0 + c) * R + r0 + r8) = o;
    }
  }
}

// ---------------------------------------------------------------------------
// Router: fp32 logits, top-2, softmax, atomic per-expert slot assignment.
// One wave per token.
// ---------------------------------------------------------------------------
__global__ __launch_bounds__(256) void k_router(
    const float* __restrict__ x, const float* __restrict__ rw,
    const float* __restrict__ rb, int* __restrict__ counts,
    int* __restrict__ meta_e, int* __restrict__ meta_idx,
    float* __restrict__ meta_p) {
  const int wv = threadIdx.x >> 6;
  const int l  = threadIdx.x & 63;
  const int tk = blockIdx.x * 4 + wv;
  const float* xr = x + (size_t)tk * DM;

  float acc[NE];
#pragma unroll
  for (int e = 0; e < NE; e++) acc[e] = 0.f;
#pragma unroll 4
  for (int i = 0; i < DM / 64; i++) {
    const float xv = xr[i * 64 + l];
#pragma unroll
    for (int e = 0; e < NE; e++) acc[e] += xv * rw[e * DM + i * 64 + l];
  }
#pragma unroll
  for (int off = 32; off > 0; off >>= 1) {
#pragma unroll
    for (int e = 0; e < NE; e++) acc[e] += __shfl_xor(acc[e], off);
  }
#pragma unroll
  for (int e = 0; e < NE; e++) acc[e] += rb[e];

  // top-2, strict > with ascending scan (ties -> lower index, matches top_k)
  float v0 = -1e30f; int e0 = 0;
#pragma unroll
  for (int e = 0; e < NE; e++) { if (acc[e] > v0) { v0 = acc[e]; e0 = e; } }
  float v1 = -1e30f; int e1 = 0;
#pragma unroll
  for (int e = 0; e < NE; e++) { if (e != e0 && acc[e] > v1) { v1 = acc[e]; e1 = e; } }
  const float p0 = 1.0f / (1.0f + __expf(v1 - v0));
  const float p1 = 1.0f - p0;

  if (l == 0) {
    const int i0 = atomicAdd(&counts[e0], 1);
    const int i1 = atomicAdd(&counts[e1], 1);
    meta_e[tk * 2 + 0] = e0;  meta_e[tk * 2 + 1] = e1;
    meta_idx[tk * 2 + 0] = i0; meta_idx[tk * 2 + 1] = i1;
    meta_p[tk * 2 + 0] = p0;  meta_p[tk * 2 + 1] = p1;
  }
}

__global__ void k_prefix(const int* __restrict__ counts, int* __restrict__ offsets) {
  if (threadIdx.x == 0) {
    int s = 0;
#pragma unroll
    for (int e = 0; e < NE; e++) { offsets[e] = s; s += counts[e]; }
  }
}

// ---------------------------------------------------------------------------
// Gather: pack token rows (fp32 -> bf16) into expert-contiguous Xg [NSLOT][DM]
// ---------------------------------------------------------------------------
__global__ __launch_bounds__(256) void k_gather(
    const float* __restrict__ x, const int* __restrict__ meta_e,
    const int* __restrict__ meta_idx, const int* __restrict__ offsets,
    unsigned short* __restrict__ Xg) {
  const int s = blockIdx.x;      // token*2 + k
  const int tk = s >> 1;
  const int e = meta_e[s];
  const int gslot = offsets[e] + meta_idx[s];
  const float4 v = ((const float4*)(x + (size_t)tk * DM))[threadIdx.x];
  ushort4 o;
  o.x = f2bf(v.x); o.y = f2bf(v.y); o.z = f2bf(v.z); o.w = f2bf(v.w);
  *(ushort4*)(Xg + (size_t)gslot * DM + threadIdx.x * 4) = o;
}

// ---------------------------------------------------------------------------
// GEMM1 fused SwiGLU: A = Xg rows [cnt][1024] bf16, Bw/Bv = [n][k] bf16;
// epilogue g = a * silu(b) -> G bf16. 128x128 tile, dual accumulators.
// ---------------------------------------------------------------------------
__global__ __launch_bounds__(256, 2) void k_gemm1(
    const unsigned short* __restrict__ Xg, const unsigned short* __restrict__ B1t,
    unsigned short* __restrict__ G, const int* __restrict__ counts,
    const int* __restrict__ offsets) {
  const int e = blockIdx.z;
  const int mt = blockIdx.y;
  const int cnt = counts[e];
  if (mt * 128 >= cnt) return;
  const int h0 = blockIdx.x * 128;
  const int off = offsets[e];
  const int row_base = off + mt * 128;

  __shared__ unsigned short As[128 * 32];
  __shared__ unsigned short Ws[128 * 32];
  __shared__ unsigned short Vs[128 * 32];

  const int t = threadIdx.x;
  const int l = t & 63;
  const int w = t >> 6;
  const int wm = (w >> 1) * 64;
  const int wn = (w & 1) * 64;
  const int lr = l & 15;
  const int kq = (l >> 4) * 8;

  const unsigned short* Bw = B1t + ((size_t)e * 4096 + h0) * DM;
  const unsigned short* Bv = Bw + (size_t)DH * DM;

  const int c0 = t, c1 = t + 256;
  const int ar0 = c0 >> 2, ak0 = (c0 & 3) * 8;
  const int ar1 = c1 >> 2, ak1 = (c1 & 3) * 8;
  const int arow0 = min(row_base + ar0, NSLOT - 1);  // clamp: no OOB reads
  const int arow1 = min(row_base + ar1, NSLOT - 1);

  f32x4 acc_a[4][4], acc_b[4][4];
  const f32x4 z4 = {0.f, 0.f, 0.f, 0.f};
#pragma unroll
  for (int i = 0; i < 4; i++)
#pragma unroll
    for (int j = 0; j < 4; j++) { acc_a[i][j] = z4; acc_b[i][j] = z4; }

  for (int k0 = 0; k0 < DM; k0 += 32) {
    __syncthreads();
    GLD16(Xg + (size_t)arow0 * DM + k0 + ak0, As + c0 * 8);
    GLD16(Xg + (size_t)arow1 * DM + k0 + ak1, As + c1 * 8);
    GLD16(Bw + (size_t)ar0 * DM + k0 + ak0, Ws + c0 * 8);
    GLD16(Bw + (size_t)ar1 * DM + k0 + ak1, Ws + c1 * 8);
    GLD16(Bv + (size_t)ar0 * DM + k0 + ak0, Vs + c0 * 8);
    GLD16(Bv + (size_t)ar1 * DM + k0 + ak1, Vs + c1 * 8);
    __syncthreads();

    bf16x8_t af[4], wf[4], vf[4];
#pragma unroll
    for (int mi = 0; mi < 4; mi++)
      af[mi] = *(const bf16x8_t*)&As[(wm + mi * 16 + lr) * 32 + kq];
#pragma unroll
    for (int ni = 0; ni < 4; ni++) {
      wf[ni] = *(const bf16x8_t*)&Ws[(wn + ni * 16 + lr) * 32 + kq];
      vf[ni] = *(const bf16x8_t*)&Vs[(wn + ni * 16 + lr) * 32 + kq];
    }
#pragma unroll
    for (int mi = 0; mi < 4; mi++)
#pragma unroll
      for (int ni = 0; ni < 4; ni++) {
        acc_a[mi][ni] = __builtin_amdgcn_mfma_f32_16x16x32_bf16(af[mi], wf[ni], acc_a[mi][ni], 0, 0, 0);
        acc_b[mi][ni] = __builtin_amdgcn_mfma_f32_16x16x32_bf16(af[mi], vf[ni], acc_b[mi][ni], 0, 0, 0);
      }
  }

  const int q4 = (l >> 4) * 4;
#pragma unroll
  for (int mi = 0; mi < 4; mi++) {
#pragma unroll
    for (int r = 0; r < 4; r++) {
      const int mloc = mt * 128 + wm + mi * 16 + q4 + r;
      if (mloc >= cnt) continue;
      unsigned short* grow = G + (size_t)(off + mloc) * DH;
#pragma unroll
      for (int ni = 0; ni < 4; ni++) {
        const int h = h0 + wn + ni * 16 + lr;
        const float a = acc_a[mi][ni][r];
        const float b = acc_b[mi][ni][r];
        const float s = b / (1.0f + __expf(-b));  // silu(b)
        grow[h] = f2bf(a * s);
      }
    }
  }
}

// ---------------------------------------------------------------------------
// GEMM2: Y = G @ W_out^T (B2t [n=1024][k=2048] bf16 per expert), plain fp32
// stores into packed Y[NSLOT][DM] (no atomics; combine does the scatter).
// ---------------------------------------------------------------------------
__global__ __launch_bounds__(256, 2) void k_gemm2(
    const unsigned short* __restrict__ G, const unsigned short* __restrict__ B2t,
    float* __restrict__ Y, const int* __restrict__ counts,
    const int* __restrict__ offsets) {
  const int e = blockIdx.z;
  const int mt = blockIdx.y;
  const int cnt = counts[e];
  if (mt * 128 >= cnt) return;
  const int n0 = blockIdx.x * 128;
  const int off = offsets[e];
  const int row_base = off + mt * 128;

  __shared__ unsigned short As[128 * 32];
  __shared__ unsigned short Bs[128 * 32];

  const int t = threadIdx.x;
  const int l = t & 63;
  const int w = t >> 6;
  const int wm = (w >> 1) * 64;
  const int wn = (w & 1) * 64;
  const int lr = l & 15;
  const int kq = (l >> 4) * 8;

  const unsigned short* Bp = B2t + ((size_t)e * DM + n0) * DH;

  const int c0 = t, c1 = t + 256;
  const int ar0 = c0 >> 2, ak0 = (c0 & 3) * 8;
  const int ar1 = c1 >> 2, ak1 = (c1 & 3) * 8;
  const int arow0 = min(row_base + ar0, NSLOT - 1);
  const int arow1 = min(row_base + ar1, NSLOT - 1);

  f32x4 acc[4][4];
  const f32x4 z4 = {0.f, 0.f, 0.f, 0.f};
#pragma unroll
  for (int i = 0; i < 4; i++)
#pragma unroll
    for (int j = 0; j < 4; j++) acc[i][j] = z4;

  for (int k0 = 0; k0 < DH; k0 += 32) {
    __syncthreads();
    GLD16(G + (size_t)arow0 * DH + k0 + ak0, As + c0 * 8);
    GLD16(G + (size_t)arow1 * DH + k0 + ak1, As + c1 * 8);
    GLD16(Bp + (size_t)ar0 * DH + k0 + ak0, Bs + c0 * 8);
    GLD16(Bp + (size_t)ar1 * DH + k0 + ak1, Bs + c1 * 8);
    __syncthreads();

    bf16x8_t af[4], bf[4];
#pragma unroll
    for (int mi = 0; mi < 4; mi++)
      af[mi] = *(const bf16x8_t*)&As[(wm + mi * 16 + lr) * 32 + kq];
#pragma unroll
    for (int ni = 0; ni < 4; ni++)
      bf[ni] = *(const bf16x8_t*)&Bs[(wn + ni * 16 + lr) * 32 + kq];
#pragma unroll
    for (int mi = 0; mi < 4; mi++)
#pragma unroll
      for (int ni = 0; ni < 4; ni++)
        acc[mi][ni] = __builtin_amdgcn_mfma_f32_16x16x32_bf16(af[mi], bf[ni], acc[mi][ni], 0, 0, 0);
  }

  const int q4 = (l >> 4) * 4;
#pragma unroll
  for (int mi = 0; mi < 4; mi++) {
#pragma unroll
    for (int r = 0; r < 4; r++) {
      const int mloc = mt * 128 + wm + mi * 16 + q4 + r;
      if (mloc >= cnt) continue;
      float* yrow = Y + (size_t)(off + mloc) * DM;
#pragma unroll
      for (int ni = 0; ni < 4; ni++)
        yrow[n0 + wn + ni * 16 + lr] = acc[mi][ni][r];
    }
  }
}

// ---------------------------------------------------------------------------
// Combine: out[tok] = p0 * Y[slot0] + p1 * Y[slot1]. One block per token.
// ---------------------------------------------------------------------------
__global__ __launch_bounds__(256) void k_combine(
    const float* __restrict__ Y, const int* __restrict__ meta_e,
    const int* __restrict__ meta_idx, const float* __restrict__ meta_p,
    const int* __restrict__ offsets, float* __restrict__ out) {
  const int tk = blockIdx.x;
  const int s0 = tk * 2, s1 = s0 + 1;
  const int g0 = offsets[meta_e[s0]] + meta_idx[s0];
  const int g1 = offsets[meta_e[s1]] + meta_idx[s1];
  const float w0 = meta_p[s0], w1 = meta_p[s1];
  const float4 a = ((const float4*)(Y + (size_t)g0 * DM))[threadIdx.x];
  const float4 b = ((const float4*)(Y + (size_t)g1 * DM))[threadIdx.x];
  float4 o;
  o.x = w0 * a.x + w1 * b.x;
  o.y = w0 * a.y + w1 * b.y;
  o.z = w0 * a.z + w1 * b.z;
  o.w = w0 * a.w + w1 * b.w;
  ((float4*)(out + (size_t)tk * DM))[threadIdx.x] = o;
}

// ---------------------------------------------------------------------------
extern "C" void kernel_launch(void* const* d_in, const int* in_sizes, int n_in,
                              void* d_out, int out_size, void* d_ws, size_t ws_size,
                              hipStream_t stream) {
  const float* x    = (const float*)d_in[0];  // [2,2048,1024]
  const float* rw   = (const float*)d_in[1];  // [8,1024]
  const float* rb   = (const float*)d_in[2];  // [8]
  const float* W    = (const float*)d_in[3];  // [8,1024,2048]
  const float* V    = (const float*)d_in[4];  // [8,1024,2048]
  const float* Wout = (const float*)d_in[5];  // [8,2048,1024]
  float* out = (float*)d_out;

  // workspace carve-up (~145 MB); Y aliases B1t (dead after gemm1)
  char* p = (char*)d_ws;
  unsigned short* B1t = (unsigned short*)p; p += (size_t)NE * 4096 * DM * 2;   // 64 MB [e][n=4096][k=1024]
  float*          Y   = (float*)B1t;                                           // 32 MB alias, [NSLOT][DM]
  unsigned short* B2t = (unsigned short*)p; p += (size_t)NE * DM * DH * 2;     // 32 MB [e][n=1024][k=2048]
  unsigned short* Xg  = (unsigned short*)p; p += (size_t)NSLOT * DM * 2;       // 16 MB
  unsigned short* G   = (unsigned short*)p; p += (size_t)NSLOT * DH * 2;       // 32 MB
  int*   counts      = (int*)p;   p += 256;
  int*   offsets     = (int*)p;   p += 256;
  int*   meta_e      = (int*)p;   p += (size_t)N_TOK * 2 * 4;
  int*   meta_idx    = (int*)p;   p += (size_t)N_TOK * 2 * 4;
  float* meta_p      = (float*)p; p += (size_t)N_TOK * 2 * 4;

  hipMemsetAsync(counts, 0, 256, stream);

  // weight transpose+convert: fp32 [k][n] -> bf16 [n][k]; W and V in one launch
  k_transpose_bf16<<<dim3(DH / 64, DM / 64, 2 * NE), 256, 0, stream>>>(
      W, V, B1t, DM, DH, (long)DM * DH, (long)4096 * DM, DH);
  k_transpose_bf16<<<dim3(DM / 64, DH / 64, NE), 256, 0, stream>>>(
      Wout, Wout, B2t, DH, DM, (long)DH * DM, (long)DM * DH, 0);

  k_router<<<N_TOK / 4, 256, 0, stream>>>(x, rw, rb, counts, meta_e, meta_idx, meta_p);
  k_prefix<<<1, 64, 0, stream>>>(counts, offsets);
  k_gather<<<NSLOT, 256, 0, stream>>>(x, meta_e, meta_idx, offsets, Xg);

  k_gemm1<<<dim3(DH / 128, NSLOT / 128, NE), 256, 0, stream>>>(Xg, B1t, G, counts, offsets);
  k_gemm2<<<dim3(DM / 128, NSLOT / 128, NE), 256, 0, stream>>>(G, B2t, Y, counts, offsets);
  k_combine<<<N_TOK, 256, 0, stream>>>(Y, meta_e, meta_idx, meta_p, offsets, out);
}

// Round 4
// 516.220 us; speedup vs baseline: 1.0587x; 1.0323x over previous
//
#include <hip/hip_runtime.h>
#include <cstdint>
#include <cstddef>

// Problem constants
#define N_TOK 4096     // B*T tokens
#define DM    1024     // d_model
#define DH    2048     // d_hidden
#define NE    8        // experts
#define NSLOT 8192     // total routed slots = N_TOK * top_k

typedef short bf16x8_t __attribute__((ext_vector_type(8)));  // 8 bf16 (4 VGPRs)
typedef float f32x4    __attribute__((ext_vector_type(4)));
typedef unsigned short u16x8 __attribute__((ext_vector_type(8)));

__device__ __forceinline__ unsigned short f2bf(float f) {
  union { float f; unsigned int u; } v; v.f = f;
  unsigned int u = v.u;
  u += 0x7fffu + ((u >> 16) & 1u);   // RNE
  return (unsigned short)(u >> 16);
}

#define GLD16(gp, lp)                                                          \
  __builtin_amdgcn_global_load_lds(                                            \
      (const __attribute__((address_space(1))) void*)(gp),                     \
      (__attribute__((address_space(3))) void*)(lp), 16, 0, 0)

// prefix-from-counts helper: returns offset of expert e, sets cnt
__device__ __forceinline__ int expert_off(const int* __restrict__ counts, int e, int* cnt) {
  int off = 0, s = 0;
#pragma unroll
  for (int i = 0; i < NE; i++) { if (i == e) off = s; s += counts[i]; }
  *cnt = counts[e];
  return off;
}

// ---------------------------------------------------------------------------
// Fused transpose + fp32->bf16 for all three weight tensors in ONE launch.
// grid = (32, 16, 24): z<8 -> W, z<16 -> V (both [DM][DH] -> B1t rows),
// z>=16 -> Wout ([DH][DM] -> B2t). 64x64 tiles, float4 reads, 16B writes,
// conflict-free LDS (verified 2-way max). Block (0,0,0) also zeroes counts
// (router runs later on the same stream).
// ---------------------------------------------------------------------------
__global__ __launch_bounds__(256) void k_transpose(
    const float* __restrict__ W, const float* __restrict__ V,
    const float* __restrict__ Wout, unsigned short* __restrict__ B1t,
    unsigned short* __restrict__ B2t, int* __restrict__ counts) {
  if (blockIdx.z == 0 && blockIdx.x == 0 && blockIdx.y == 0 && threadIdx.x < NE)
    counts[threadIdx.x] = 0;

  const int z = blockIdx.z;
  const float* s;
  unsigned short* d;
  int R, C, xt, yt;
  if (z < 16) {
    const int e = z & 7;
    s = ((z < 8) ? W : V) + (size_t)e * DM * DH;
    d = B1t + (size_t)e * 4096 * DM + (size_t)((z < 8) ? 0 : DH) * DM;
    R = DM; C = DH; xt = blockIdx.x; yt = blockIdx.y;      // 32 x 16 tiles
  } else {
    const int e = z - 16;
    s = Wout + (size_t)e * DH * DM;
    d = B2t + (size_t)e * DM * DH;
    R = DH; C = DM;
    const int flat = blockIdx.x * 16 + blockIdx.y;          // 0..511 = 16 x 32
    xt = flat & 15; yt = flat >> 4;
  }
  const int c0 = xt * 64, r0 = yt * 64;
  __shared__ float tile[64][65];
  const int t = threadIdx.x;
  {
    const int cc = (t & 15) * 4;
#pragma unroll
    for (int j = 0; j < 4; j++) {
      const int r = (t >> 4) + j * 16;
      const float4 v = *(const float4*)(s + (size_t)(r0 + r) * C + c0 + cc);
      tile[r][cc + 0] = v.x; tile[r][cc + 1] = v.y;
      tile[r][cc + 2] = v.z; tile[r][cc + 3] = v.w;
    }
  }
  __syncthreads();
  {
    const int r8 = (t & 7) * 8;
#pragma unroll
    for (int j = 0; j < 2; j++) {
      const int c = (t >> 3) + j * 32;
      u16x8 o;
#pragma unroll
      for (int i = 0; i < 8; i++) o[i] = f2bf(tile[r8 + i][c]);
      *(u16x8*)(d + (size_t)(c0 + c) * R + r0 + r8) = o;
    }
  }
}

// ---------------------------------------------------------------------------
// Router: fp32 logits, top-2, softmax, atomic per-expert slot assignment.
// One wave per token.
// ---------------------------------------------------------------------------
__global__ __launch_bounds__(256) void k_router(
    const float* __restrict__ x, const float* __restrict__ rw,
    const float* __restrict__ rb, int* __restrict__ counts,
    int* __restrict__ meta_e, int* __restrict__ meta_idx,
    float* __restrict__ meta_p) {
  const int wv = threadIdx.x >> 6;
  const int l  = threadIdx.x & 63;
  const int tk = blockIdx.x * 4 + wv;
  const float* xr = x + (size_t)tk * DM;

  float acc[NE];
#pragma unroll
  for (int e = 0; e < NE; e++) acc[e] = 0.f;
#pragma unroll 4
  for (int i = 0; i < DM / 64; i++) {
    const float xv = xr[i * 64 + l];
#pragma unroll
    for (int e = 0; e < NE; e++) acc[e] += xv * rw[e * DM + i * 64 + l];
  }
#pragma unroll
  for (int off = 32; off > 0; off >>= 1) {
#pragma unroll
    for (int e = 0; e < NE; e++) acc[e] += __shfl_xor(acc[e], off);
  }
#pragma unroll
  for (int e = 0; e < NE; e++) acc[e] += rb[e];

  // top-2, strict > ascending scan (ties -> lower index, matches top_k)
  float v0 = -1e30f; int e0 = 0;
#pragma unroll
  for (int e = 0; e < NE; e++) { if (acc[e] > v0) { v0 = acc[e]; e0 = e; } }
  float v1 = -1e30f; int e1 = 0;
#pragma unroll
  for (int e = 0; e < NE; e++) { if (e != e0 && acc[e] > v1) { v1 = acc[e]; e1 = e; } }
  const float p0 = 1.0f / (1.0f + __expf(v1 - v0));
  const float p1 = 1.0f - p0;

  if (l == 0) {
    const int i0 = atomicAdd(&counts[e0], 1);
    const int i1 = atomicAdd(&counts[e1], 1);
    meta_e[tk * 2 + 0] = e0;  meta_e[tk * 2 + 1] = e1;
    meta_idx[tk * 2 + 0] = i0; meta_idx[tk * 2 + 1] = i1;
    meta_p[tk * 2 + 0] = p0;  meta_p[tk * 2 + 1] = p1;
  }
}

// ---------------------------------------------------------------------------
// Gather: one block per TOKEN; read x row once, write both routed slots.
// Offsets computed inline from counts (prefix kernel eliminated).
// ---------------------------------------------------------------------------
__global__ __launch_bounds__(256) void k_gather(
    const float* __restrict__ x, const int* __restrict__ meta_e,
    const int* __restrict__ meta_idx, const int* __restrict__ counts,
    unsigned short* __restrict__ Xg) {
  const int tk = blockIdx.x;
  int offs[NE];
  { int s = 0;
#pragma unroll
    for (int e = 0; e < NE; e++) { offs[e] = s; s += counts[e]; } }
  const int s0 = tk * 2, s1 = s0 + 1;
  const int g0 = offs[meta_e[s0]] + meta_idx[s0];
  const int g1 = offs[meta_e[s1]] + meta_idx[s1];
  const float4 v = ((const float4*)(x + (size_t)tk * DM))[threadIdx.x];
  ushort4 o;
  o.x = f2bf(v.x); o.y = f2bf(v.y); o.z = f2bf(v.z); o.w = f2bf(v.w);
  *(ushort4*)(Xg + (size_t)g0 * DM + threadIdx.x * 4) = o;
  *(ushort4*)(Xg + (size_t)g1 * DM + threadIdx.x * 4) = o;
}

// ---------------------------------------------------------------------------
// GEMM1 fused SwiGLU: A = Xg rows [cnt][1024] bf16, Bw/Bv = [n][k] bf16;
// epilogue g = a * silu(b) -> G bf16. 128x128 tile, dual accumulators.
// ---------------------------------------------------------------------------
__global__ __launch_bounds__(256, 2) void k_gemm1(
    const unsigned short* __restrict__ Xg, const unsigned short* __restrict__ B1t,
    unsigned short* __restrict__ G, const int* __restrict__ counts) {
  const int e = blockIdx.z;
  int cnt;
  const int off = expert_off(counts, e, &cnt);
  const int mt = blockIdx.y;
  if (mt * 128 >= cnt) return;
  const int h0 = blockIdx.x * 128;
  const int row_base = off + mt * 128;

  __shared__ unsigned short As[128 * 32];
  __shared__ unsigned short Ws[128 * 32];
  __shared__ unsigned short Vs[128 * 32];

  const int t = threadIdx.x;
  const int l = t & 63;
  const int w = t >> 6;
  const int wm = (w >> 1) * 64;
  const int wn = (w & 1) * 64;
  const int lr = l & 15;
  const int kq = (l >> 4) * 8;

  const unsigned short* Bw = B1t + ((size_t)e * 4096 + h0) * DM;
  const unsigned short* Bv = Bw + (size_t)DH * DM;

  const int c0 = t, c1 = t + 256;
  const int ar0 = c0 >> 2, ak0 = (c0 & 3) * 8;
  const int ar1 = c1 >> 2, ak1 = (c1 & 3) * 8;
  const int arow0 = min(row_base + ar0, NSLOT - 1);  // clamp: no OOB reads
  const int arow1 = min(row_base + ar1, NSLOT - 1);

  f32x4 acc_a[4][4], acc_b[4][4];
  const f32x4 z4 = {0.f, 0.f, 0.f, 0.f};
#pragma unroll
  for (int i = 0; i < 4; i++)
#pragma unroll
    for (int j = 0; j < 4; j++) { acc_a[i][j] = z4; acc_b[i][j] = z4; }

  for (int k0 = 0; k0 < DM; k0 += 32) {
    __syncthreads();
    GLD16(Xg + (size_t)arow0 * DM + k0 + ak0, As + c0 * 8);
    GLD16(Xg + (size_t)arow1 * DM + k0 + ak1, As + c1 * 8);
    GLD16(Bw + (size_t)ar0 * DM + k0 + ak0, Ws + c0 * 8);
    GLD16(Bw + (size_t)ar1 * DM + k0 + ak1, Ws + c1 * 8);
    GLD16(Bv + (size_t)ar0 * DM + k0 + ak0, Vs + c0 * 8);
    GLD16(Bv + (size_t)ar1 * DM + k0 + ak1, Vs + c1 * 8);
    __syncthreads();

    bf16x8_t af[4], wf[4], vf[4];
#pragma unroll
    for (int mi = 0; mi < 4; mi++)
      af[mi] = *(const bf16x8_t*)&As[(wm + mi * 16 + lr) * 32 + kq];
#pragma unroll
    for (int ni = 0; ni < 4; ni++) {
      wf[ni] = *(const bf16x8_t*)&Ws[(wn + ni * 16 + lr) * 32 + kq];
      vf[ni] = *(const bf16x8_t*)&Vs[(wn + ni * 16 + lr) * 32 + kq];
    }
#pragma unroll
    for (int mi = 0; mi < 4; mi++)
#pragma unroll
      for (int ni = 0; ni < 4; ni++) {
        acc_a[mi][ni] = __builtin_amdgcn_mfma_f32_16x16x32_bf16(af[mi], wf[ni], acc_a[mi][ni], 0, 0, 0);
        acc_b[mi][ni] = __builtin_amdgcn_mfma_f32_16x16x32_bf16(af[mi], vf[ni], acc_b[mi][ni], 0, 0, 0);
      }
  }

  const int q4 = (l >> 4) * 4;
#pragma unroll
  for (int mi = 0; mi < 4; mi++) {
#pragma unroll
    for (int r = 0; r < 4; r++) {
      const int mloc = mt * 128 + wm + mi * 16 + q4 + r;
      if (mloc >= cnt) continue;
      unsigned short* grow = G + (size_t)(off + mloc) * DH;
#pragma unroll
      for (int ni = 0; ni < 4; ni++) {
        const int h = h0 + wn + ni * 16 + lr;
        const float a = acc_a[mi][ni][r];
        const float b = acc_b[mi][ni][r];
        const float s = b / (1.0f + __expf(-b));  // silu(b)
        grow[h] = f2bf(a * s);
      }
    }
  }
}

// ---------------------------------------------------------------------------
// GEMM2, SPLIT-K (2 halves of K=2048): Y_half = G[:, half] @ W_out_half^T.
// Doubles active blocks (2 -> 4 per CU) at constant MFMA:staging ratio —
// the K-loop barrier drain is otherwise exposed at 2 blocks/CU.
// Plain fp32 stores into Y[half][NSLOT][DM]; combine sums halves.
// ---------------------------------------------------------------------------
__global__ __launch_bounds__(256, 2) void k_gemm2(
    const unsigned short* __restrict__ G, const unsigned short* __restrict__ B2t,
    float* __restrict__ Y, const int* __restrict__ counts) {
  const int z = blockIdx.z;
  const int e = z & 7;
  const int half = z >> 3;
  int cnt;
  const int off = expert_off(counts, e, &cnt);
  const int mt = blockIdx.y;
  if (mt * 128 >= cnt) return;
  const int n0 = blockIdx.x * 128;
  const int row_base = off + mt * 128;
  const int kbase = half * 1024;

  __shared__ unsigned short As[128 * 32];
  __shared__ unsigned short Bs[128 * 32];

  const int t = threadIdx.x;
  const int l = t & 63;
  const int w = t >> 6;
  const int wm = (w >> 1) * 64;
  const int wn = (w & 1) * 64;
  const int lr = l & 15;
  const int kq = (l >> 4) * 8;

  const unsigned short* Bp = B2t + ((size_t)e * DM + n0) * DH;

  const int c0 = t, c1 = t + 256;
  const int ar0 = c0 >> 2, ak0 = (c0 & 3) * 8;
  const int ar1 = c1 >> 2, ak1 = (c1 & 3) * 8;
  const int arow0 = min(row_base + ar0, NSLOT - 1);
  const int arow1 = min(row_base + ar1, NSLOT - 1);

  f32x4 acc[4][4];
  const f32x4 z4 = {0.f, 0.f, 0.f, 0.f};
#pragma unroll
  for (int i = 0; i < 4; i++)
#pragma unroll
    for (int j = 0; j < 4; j++) acc[i][j] = z4;

  for (int kk = 0; kk < 1024; kk += 32) {
    const int k0 = kbase + kk;
    __syncthreads();
    GLD16(G + (size_t)arow0 * DH + k0 + ak0, As + c0 * 8);
    GLD16(G + (size_t)arow1 * DH + k0 + ak1, As + c1 * 8);
    GLD16(Bp + (size_t)ar0 * DH + k0 + ak0, Bs + c0 * 8);
    GLD16(Bp + (size_t)ar1 * DH + k0 + ak1, Bs + c1 * 8);
    __syncthreads();

    bf16x8_t af[4], bf[4];
#pragma unroll
    for (int mi = 0; mi < 4; mi++)
      af[mi] = *(const bf16x8_t*)&As[(wm + mi * 16 + lr) * 32 + kq];
#pragma unroll
    for (int ni = 0; ni < 4; ni++)
      bf[ni] = *(const bf16x8_t*)&Bs[(wn + ni * 16 + lr) * 32 + kq];
#pragma unroll
    for (int mi = 0; mi < 4; mi++)
#pragma unroll
      for (int ni = 0; ni < 4; ni++)
        acc[mi][ni] = __builtin_amdgcn_mfma_f32_16x16x32_bf16(af[mi], bf[ni], acc[mi][ni], 0, 0, 0);
  }

  float* Yh = Y + (size_t)half * NSLOT * DM;
  const int q4 = (l >> 4) * 4;
#pragma unroll
  for (int mi = 0; mi < 4; mi++) {
#pragma unroll
    for (int r = 0; r < 4; r++) {
      const int mloc = mt * 128 + wm + mi * 16 + q4 + r;
      if (mloc >= cnt) continue;
      float* yrow = Yh + (size_t)(off + mloc) * DM;
#pragma unroll
      for (int ni = 0; ni < 4; ni++)
        yrow[n0 + wn + ni * 16 + lr] = acc[mi][ni][r];
    }
  }
}

// ---------------------------------------------------------------------------
// Combine: out[tok] = p0*(Y0[g0]+Y1[g0]) + p1*(Y0[g1]+Y1[g1]).
// ---------------------------------------------------------------------------
__global__ __launch_bounds__(256) void k_combine(
    const float* __restrict__ Y, const int* __restrict__ meta_e,
    const int* __restrict__ meta_idx, const float* __restrict__ meta_p,
    const int* __restrict__ counts, float* __restrict__ out) {
  const int tk = blockIdx.x;
  int offs[NE];
  { int s = 0;
#pragma unroll
    for (int e = 0; e < NE; e++) { offs[e] = s; s += counts[e]; } }
  const int s0 = tk * 2, s1 = s0 + 1;
  const int g0 = offs[meta_e[s0]] + meta_idx[s0];
  const int g1 = offs[meta_e[s1]] + meta_idx[s1];
  const float w0 = meta_p[s0], w1 = meta_p[s1];
  const float* Y1 = Y + (size_t)NSLOT * DM;
  const float4 a0 = ((const float4*)(Y  + (size_t)g0 * DM))[threadIdx.x];
  const float4 a1 = ((const float4*)(Y1 + (size_t)g0 * DM))[threadIdx.x];
  const float4 b0 = ((const float4*)(Y  + (size_t)g1 * DM))[threadIdx.x];
  const float4 b1 = ((const float4*)(Y1 + (size_t)g1 * DM))[threadIdx.x];
  float4 o;
  o.x = w0 * (a0.x + a1.x) + w1 * (b0.x + b1.x);
  o.y = w0 * (a0.y + a1.y) + w1 * (b0.y + b1.y);
  o.z = w0 * (a0.z + a1.z) + w1 * (b0.z + b1.z);
  o.w = w0 * (a0.w + a1.w) + w1 * (b0.w + b1.w);
  ((float4*)(out + (size_t)tk * DM))[threadIdx.x] = o;
}

// ---------------------------------------------------------------------------
extern "C" void kernel_launch(void* const* d_in, const int* in_sizes, int n_in,
                              void* d_out, int out_size, void* d_ws, size_t ws_size,
                              hipStream_t stream) {
  const float* x    = (const float*)d_in[0];  // [2,2048,1024]
  const float* rw   = (const float*)d_in[1];  // [8,1024]
  const float* rb   = (const float*)d_in[2];  // [8]
  const float* W    = (const float*)d_in[3];  // [8,1024,2048]
  const float* V    = (const float*)d_in[4];  // [8,1024,2048]
  const float* Wout = (const float*)d_in[5];  // [8,2048,1024]
  float* out = (float*)d_out;

  // workspace carve-up (~145 MB); Y (2 x 32 MB fp32) aliases B1t (64 MB,
  // dead after gemm1)
  char* p = (char*)d_ws;
  unsigned short* B1t = (unsigned short*)p; p += (size_t)NE * 4096 * DM * 2;   // 64 MB [e][n=4096][k=1024]
  float*          Y   = (float*)B1t;                                           // alias: [2][NSLOT][DM]
  unsigned short* B2t = (unsigned short*)p; p += (size_t)NE * DM * DH * 2;     // 32 MB [e][n=1024][k=2048]
  unsigned short* Xg  = (unsigned short*)p; p += (size_t)NSLOT * DM * 2;       // 16 MB
  unsigned short* G   = (unsigned short*)p; p += (size_t)NSLOT * DH * 2;       // 32 MB
  int*   counts      = (int*)p;   p += 256;
  int*   meta_e      = (int*)p;   p += (size_t)N_TOK * 2 * 4;
  int*   meta_idx    = (int*)p;   p += (size_t)N_TOK * 2 * 4;
  float* meta_p      = (float*)p; p += (size_t)N_TOK * 2 * 4;

  // 6 graph nodes total (was 10)
  k_transpose<<<dim3(32, 16, 24), 256, 0, stream>>>(W, V, Wout, B1t, B2t, counts);
  k_router<<<N_TOK / 4, 256, 0, stream>>>(x, rw, rb, counts, meta_e, meta_idx, meta_p);
  k_gather<<<N_TOK, 256, 0, stream>>>(x, meta_e, meta_idx, counts, Xg);
  k_gemm1<<<dim3(DH / 128, NSLOT / 128, NE), 256, 0, stream>>>(Xg, B1t, G, counts);
  k_gemm2<<<dim3(DM / 128, NSLOT / 128, 2 * NE), 256, 0, stream>>>(G, B2t, Y, counts);
  k_combine<<<N_TOK, 256, 0, stream>>>(Y, meta_e, meta_idx, meta_p, counts, out);
}

// Round 5
// 492.880 us; speedup vs baseline: 1.1088x; 1.0474x over previous
//
#include <hip/hip_runtime.h>
#include <cstdint>
#include <cstddef>

// Problem constants
#define N_TOK 4096     // B*T tokens
#define DM    1024     // d_model
#define DH    2048     // d_hidden
#define NE    8        // experts
#define NSLOT 8192     // total routed slots = N_TOK * top_k

typedef short bf16x8_t __attribute__((ext_vector_type(8)));  // 8 bf16 (4 VGPRs)
typedef float f32x4    __attribute__((ext_vector_type(4)));
typedef unsigned short u16x8 __attribute__((ext_vector_type(8)));

__device__ __forceinline__ unsigned short f2bf(float f) {
  union { float f; unsigned int u; } v; v.f = f;
  unsigned int u = v.u;
  u += 0x7fffu + ((u >> 16) & 1u);   // RNE
  return (unsigned short)(u >> 16);
}

__device__ __forceinline__ float bf2f(unsigned short h) {
  union { unsigned int u; float f; } v; v.u = ((unsigned int)h) << 16;
  return v.f;
}

#define GLD16(gp, lp)                                                          \
  __builtin_amdgcn_global_load_lds(                                            \
      (const __attribute__((address_space(1))) void*)(gp),                     \
      (__attribute__((address_space(3))) void*)(lp), 16, 0, 0)

// prefix-from-counts helper: returns offset of expert e, sets cnt
__device__ __forceinline__ int expert_off(const int* __restrict__ counts, int e, int* cnt) {
  int off = 0, s = 0;
#pragma unroll
  for (int i = 0; i < NE; i++) { if (i == e) off = s; s += counts[i]; }
  *cnt = counts[e];
  return off;
}

// ---------------------------------------------------------------------------
// Fused transpose + fp32->bf16 for all three weight tensors in ONE launch.
// grid = (32, 16, 24): z<8 -> W, z<16 -> V (both [DM][DH] -> B1t rows),
// z>=16 -> Wout ([DH][DM] -> B2t). 64x64 tiles, float4 reads, 16B writes.
// Block (0,0,0) also zeroes counts (router runs later on the same stream).
// ---------------------------------------------------------------------------
__global__ __launch_bounds__(256) void k_transpose(
    const float* __restrict__ W, const float* __restrict__ V,
    const float* __restrict__ Wout, unsigned short* __restrict__ B1t,
    unsigned short* __restrict__ B2t, int* __restrict__ counts) {
  if (blockIdx.z == 0 && blockIdx.x == 0 && blockIdx.y == 0 && threadIdx.x < NE)
    counts[threadIdx.x] = 0;

  const int z = blockIdx.z;
  const float* s;
  unsigned short* d;
  int R, C, xt, yt;
  if (z < 16) {
    const int e = z & 7;
    s = ((z < 8) ? W : V) + (size_t)e * DM * DH;
    d = B1t + (size_t)e * 4096 * DM + (size_t)((z < 8) ? 0 : DH) * DM;
    R = DM; C = DH; xt = blockIdx.x; yt = blockIdx.y;      // 32 x 16 tiles
  } else {
    const int e = z - 16;
    s = Wout + (size_t)e * DH * DM;
    d = B2t + (size_t)e * DM * DH;
    R = DH; C = DM;
    const int flat = blockIdx.x * 16 + blockIdx.y;          // 0..511 = 16 x 32
    xt = flat & 15; yt = flat >> 4;
  }
  const int c0 = xt * 64, r0 = yt * 64;
  __shared__ float tile[64][65];
  const int t = threadIdx.x;
  {
    const int cc = (t & 15) * 4;
#pragma unroll
    for (int j = 0; j < 4; j++) {
      const int r = (t >> 4) + j * 16;
      const float4 v = *(const float4*)(s + (size_t)(r0 + r) * C + c0 + cc);
      tile[r][cc + 0] = v.x; tile[r][cc + 1] = v.y;
      tile[r][cc + 2] = v.z; tile[r][cc + 3] = v.w;
    }
  }
  __syncthreads();
  {
    const int r8 = (t & 7) * 8;
#pragma unroll
    for (int j = 0; j < 2; j++) {
      const int c = (t >> 3) + j * 32;
      u16x8 o;
#pragma unroll
      for (int i = 0; i < 8; i++) o[i] = f2bf(tile[r8 + i][c]);
      *(u16x8*)(d + (size_t)(c0 + c) * R + r0 + r8) = o;
    }
  }
}

// ---------------------------------------------------------------------------
// Router: fp32 logits, top-2, softmax, atomic per-expert slot assignment.
// One wave per token.
// ---------------------------------------------------------------------------
__global__ __launch_bounds__(256) void k_router(
    const float* __restrict__ x, const float* __restrict__ rw,
    const float* __restrict__ rb, int* __restrict__ counts,
    int* __restrict__ meta_e, int* __restrict__ meta_idx,
    float* __restrict__ meta_p) {
  const int wv = threadIdx.x >> 6;
  const int l  = threadIdx.x & 63;
  const int tk = blockIdx.x * 4 + wv;
  const float* xr = x + (size_t)tk * DM;

  float acc[NE];
#pragma unroll
  for (int e = 0; e < NE; e++) acc[e] = 0.f;
#pragma unroll 4
  for (int i = 0; i < DM / 64; i++) {
    const float xv = xr[i * 64 + l];
#pragma unroll
    for (int e = 0; e < NE; e++) acc[e] += xv * rw[e * DM + i * 64 + l];
  }
#pragma unroll
  for (int off = 32; off > 0; off >>= 1) {
#pragma unroll
    for (int e = 0; e < NE; e++) acc[e] += __shfl_xor(acc[e], off);
  }
#pragma unroll
  for (int e = 0; e < NE; e++) acc[e] += rb[e];

  // top-2, strict > ascending scan (ties -> lower index, matches top_k)
  float v0 = -1e30f; int e0 = 0;
#pragma unroll
  for (int e = 0; e < NE; e++) { if (acc[e] > v0) { v0 = acc[e]; e0 = e; } }
  float v1 = -1e30f; int e1 = 0;
#pragma unroll
  for (int e = 0; e < NE; e++) { if (e != e0 && acc[e] > v1) { v1 = acc[e]; e1 = e; } }
  const float p0 = 1.0f / (1.0f + __expf(v1 - v0));
  const float p1 = 1.0f - p0;

  if (l == 0) {
    const int i0 = atomicAdd(&counts[e0], 1);
    const int i1 = atomicAdd(&counts[e1], 1);
    meta_e[tk * 2 + 0] = e0;  meta_e[tk * 2 + 1] = e1;
    meta_idx[tk * 2 + 0] = i0; meta_idx[tk * 2 + 1] = i1;
    meta_p[tk * 2 + 0] = p0;  meta_p[tk * 2 + 1] = p1;
  }
}

// ---------------------------------------------------------------------------
// Gather: one block per TOKEN; read x row once, write both routed slots.
// ---------------------------------------------------------------------------
__global__ __launch_bounds__(256) void k_gather(
    const float* __restrict__ x, const int* __restrict__ meta_e,
    const int* __restrict__ meta_idx, const int* __restrict__ counts,
    unsigned short* __restrict__ Xg) {
  const int tk = blockIdx.x;
  int offs[NE];
  { int s = 0;
#pragma unroll
    for (int e = 0; e < NE; e++) { offs[e] = s; s += counts[e]; } }
  const int s0 = tk * 2, s1 = s0 + 1;
  const int g0 = offs[meta_e[s0]] + meta_idx[s0];
  const int g1 = offs[meta_e[s1]] + meta_idx[s1];
  const float4 v = ((const float4*)(x + (size_t)tk * DM))[threadIdx.x];
  ushort4 o;
  o.x = f2bf(v.x); o.y = f2bf(v.y); o.z = f2bf(v.z); o.w = f2bf(v.w);
  *(ushort4*)(Xg + (size_t)g0 * DM + threadIdx.x * 4) = o;
  *(ushort4*)(Xg + (size_t)g1 * DM + threadIdx.x * 4) = o;
}

// ---------------------------------------------------------------------------
// GEMM1 fused SwiGLU, BK=64 as two 128x32 sub-tiles (halves barrier count at
// unchanged occupancy: LDS 48 KB x 2 blocks = 96 KB <= 160; occupancy is
// VGPR-capped at 2 blocks/CU anyway). Epilogue g = a * silu(b) -> G bf16.
// ---------------------------------------------------------------------------
__global__ __launch_bounds__(256, 2) void k_gemm1(
    const unsigned short* __restrict__ Xg, const unsigned short* __restrict__ B1t,
    unsigned short* __restrict__ G, const int* __restrict__ counts) {
  const int e = blockIdx.z;
  int cnt;
  const int off = expert_off(counts, e, &cnt);
  const int mt = blockIdx.y;
  if (mt * 128 >= cnt) return;
  const int h0 = blockIdx.x * 128;
  const int row_base = off + mt * 128;

  __shared__ unsigned short As[2][128 * 32];
  __shared__ unsigned short Ws[2][128 * 32];
  __shared__ unsigned short Vs[2][128 * 32];

  const int t = threadIdx.x;
  const int l = t & 63;
  const int w = t >> 6;
  const int wm = (w >> 1) * 64;
  const int wn = (w & 1) * 64;
  const int lr = l & 15;
  const int kq = (l >> 4) * 8;

  const unsigned short* Bw = B1t + ((size_t)e * 4096 + h0) * DM;
  const unsigned short* Bv = Bw + (size_t)DH * DM;

  const int c0 = t, c1 = t + 256;
  const int ar0 = c0 >> 2, ak0 = (c0 & 3) * 8;
  const int ar1 = c1 >> 2, ak1 = (c1 & 3) * 8;
  const int arow0 = min(row_base + ar0, NSLOT - 1);  // clamp: no OOB reads
  const int arow1 = min(row_base + ar1, NSLOT - 1);

  f32x4 acc_a[4][4], acc_b[4][4];
  const f32x4 z4 = {0.f, 0.f, 0.f, 0.f};
#pragma unroll
  for (int i = 0; i < 4; i++)
#pragma unroll
    for (int j = 0; j < 4; j++) { acc_a[i][j] = z4; acc_b[i][j] = z4; }

  for (int k0 = 0; k0 < DM; k0 += 64) {
    __syncthreads();
    GLD16(Xg + (size_t)arow0 * DM + k0 + ak0,      &As[0][c0 * 8]);
    GLD16(Xg + (size_t)arow1 * DM + k0 + ak1,      &As[0][c1 * 8]);
    GLD16(Xg + (size_t)arow0 * DM + k0 + 32 + ak0, &As[1][c0 * 8]);
    GLD16(Xg + (size_t)arow1 * DM + k0 + 32 + ak1, &As[1][c1 * 8]);
    GLD16(Bw + (size_t)ar0 * DM + k0 + ak0,        &Ws[0][c0 * 8]);
    GLD16(Bw + (size_t)ar1 * DM + k0 + ak1,        &Ws[0][c1 * 8]);
    GLD16(Bw + (size_t)ar0 * DM + k0 + 32 + ak0,   &Ws[1][c0 * 8]);
    GLD16(Bw + (size_t)ar1 * DM + k0 + 32 + ak1,   &Ws[1][c1 * 8]);
    GLD16(Bv + (size_t)ar0 * DM + k0 + ak0,        &Vs[0][c0 * 8]);
    GLD16(Bv + (size_t)ar1 * DM + k0 + ak1,        &Vs[0][c1 * 8]);
    GLD16(Bv + (size_t)ar0 * DM + k0 + 32 + ak0,   &Vs[1][c0 * 8]);
    GLD16(Bv + (size_t)ar1 * DM + k0 + 32 + ak1,   &Vs[1][c1 * 8]);
    __syncthreads();

#pragma unroll
    for (int ks = 0; ks < 2; ks++) {
      bf16x8_t af[4], wf[4], vf[4];
#pragma unroll
      for (int mi = 0; mi < 4; mi++)
        af[mi] = *(const bf16x8_t*)&As[ks][(wm + mi * 16 + lr) * 32 + kq];
#pragma unroll
      for (int ni = 0; ni < 4; ni++) {
        wf[ni] = *(const bf16x8_t*)&Ws[ks][(wn + ni * 16 + lr) * 32 + kq];
        vf[ni] = *(const bf16x8_t*)&Vs[ks][(wn + ni * 16 + lr) * 32 + kq];
      }
#pragma unroll
      for (int mi = 0; mi < 4; mi++)
#pragma unroll
        for (int ni = 0; ni < 4; ni++) {
          acc_a[mi][ni] = __builtin_amdgcn_mfma_f32_16x16x32_bf16(af[mi], wf[ni], acc_a[mi][ni], 0, 0, 0);
          acc_b[mi][ni] = __builtin_amdgcn_mfma_f32_16x16x32_bf16(af[mi], vf[ni], acc_b[mi][ni], 0, 0, 0);
        }
    }
  }

  const int q4 = (l >> 4) * 4;
#pragma unroll
  for (int mi = 0; mi < 4; mi++) {
#pragma unroll
    for (int r = 0; r < 4; r++) {
      const int mloc = mt * 128 + wm + mi * 16 + q4 + r;
      if (mloc >= cnt) continue;
      unsigned short* grow = G + (size_t)(off + mloc) * DH;
#pragma unroll
      for (int ni = 0; ni < 4; ni++) {
        const int h = h0 + wn + ni * 16 + lr;
        const float a = acc_a[mi][ni][r];
        const float b = acc_b[mi][ni][r];
        const float s = b / (1.0f + __expf(-b));  // silu(b)
        grow[h] = f2bf(a * s);
      }
    }
  }
}

// ---------------------------------------------------------------------------
// GEMM2, split-K (2 halves of K=2048), BK=64 sub-tiled, bf16 Y partials.
// ---------------------------------------------------------------------------
__global__ __launch_bounds__(256, 2) void k_gemm2(
    const unsigned short* __restrict__ G, const unsigned short* __restrict__ B2t,
    unsigned short* __restrict__ Y, const int* __restrict__ counts) {
  const int z = blockIdx.z;
  const int e = z & 7;
  const int half = z >> 3;
  int cnt;
  const int off = expert_off(counts, e, &cnt);
  const int mt = blockIdx.y;
  if (mt * 128 >= cnt) return;
  const int n0 = blockIdx.x * 128;
  const int row_base = off + mt * 128;
  const int kbase = half * 1024;

  __shared__ unsigned short As[2][128 * 32];
  __shared__ unsigned short Bs[2][128 * 32];

  const int t = threadIdx.x;
  const int l = t & 63;
  const int w = t >> 6;
  const int wm = (w >> 1) * 64;
  const int wn = (w & 1) * 64;
  const int lr = l & 15;
  const int kq = (l >> 4) * 8;

  const unsigned short* Bp = B2t + ((size_t)e * DM + n0) * DH;

  const int c0 = t, c1 = t + 256;
  const int ar0 = c0 >> 2, ak0 = (c0 & 3) * 8;
  const int ar1 = c1 >> 2, ak1 = (c1 & 3) * 8;
  const int arow0 = min(row_base + ar0, NSLOT - 1);
  const int arow1 = min(row_base + ar1, NSLOT - 1);

  f32x4 acc[4][4];
  const f32x4 z4 = {0.f, 0.f, 0.f, 0.f};
#pragma unroll
  for (int i = 0; i < 4; i++)
#pragma unroll
    for (int j = 0; j < 4; j++) acc[i][j] = z4;

  for (int kk = 0; kk < 1024; kk += 64) {
    const int k0 = kbase + kk;
    __syncthreads();
    GLD16(G + (size_t)arow0 * DH + k0 + ak0,      &As[0][c0 * 8]);
    GLD16(G + (size_t)arow1 * DH + k0 + ak1,      &As[0][c1 * 8]);
    GLD16(G + (size_t)arow0 * DH + k0 + 32 + ak0, &As[1][c0 * 8]);
    GLD16(G + (size_t)arow1 * DH + k0 + 32 + ak1, &As[1][c1 * 8]);
    GLD16(Bp + (size_t)ar0 * DH + k0 + ak0,       &Bs[0][c0 * 8]);
    GLD16(Bp + (size_t)ar1 * DH + k0 + ak1,       &Bs[0][c1 * 8]);
    GLD16(Bp + (size_t)ar0 * DH + k0 + 32 + ak0,  &Bs[1][c0 * 8]);
    GLD16(Bp + (size_t)ar1 * DH + k0 + 32 + ak1,  &Bs[1][c1 * 8]);
    __syncthreads();

#pragma unroll
    for (int ks = 0; ks < 2; ks++) {
      bf16x8_t af[4], bf[4];
#pragma unroll
      for (int mi = 0; mi < 4; mi++)
        af[mi] = *(const bf16x8_t*)&As[ks][(wm + mi * 16 + lr) * 32 + kq];
#pragma unroll
      for (int ni = 0; ni < 4; ni++)
        bf[ni] = *(const bf16x8_t*)&Bs[ks][(wn + ni * 16 + lr) * 32 + kq];
#pragma unroll
      for (int mi = 0; mi < 4; mi++)
#pragma unroll
        for (int ni = 0; ni < 4; ni++)
          acc[mi][ni] = __builtin_amdgcn_mfma_f32_16x16x32_bf16(af[mi], bf[ni], acc[mi][ni], 0, 0, 0);
    }
  }

  unsigned short* Yh = Y + (size_t)half * NSLOT * DM;
  const int q4 = (l >> 4) * 4;
#pragma unroll
  for (int mi = 0; mi < 4; mi++) {
#pragma unroll
    for (int r = 0; r < 4; r++) {
      const int mloc = mt * 128 + wm + mi * 16 + q4 + r;
      if (mloc >= cnt) continue;
      unsigned short* yrow = Yh + (size_t)(off + mloc) * DM;
#pragma unroll
      for (int ni = 0; ni < 4; ni++)
        yrow[n0 + wn + ni * 16 + lr] = f2bf(acc[mi][ni][r]);
    }
  }
}

// ---------------------------------------------------------------------------
// Combine: out[tok] = p0*(Y0[g0]+Y1[g0]) + p1*(Y0[g1]+Y1[g1]); Y is bf16.
// ---------------------------------------------------------------------------
__global__ __launch_bounds__(256) void k_combine(
    const unsigned short* __restrict__ Y, const int* __restrict__ meta_e,
    const int* __restrict__ meta_idx, const float* __restrict__ meta_p,
    const int* __restrict__ counts, float* __restrict__ out) {
  const int tk = blockIdx.x;
  int offs[NE];
  { int s = 0;
#pragma unroll
    for (int e = 0; e < NE; e++) { offs[e] = s; s += counts[e]; } }
  const int s0 = tk * 2, s1 = s0 + 1;
  const int g0 = offs[meta_e[s0]] + meta_idx[s0];
  const int g1 = offs[meta_e[s1]] + meta_idx[s1];
  const float w0 = meta_p[s0], w1 = meta_p[s1];
  const unsigned short* Y1 = Y + (size_t)NSLOT * DM;
  const ushort4 a0 = ((const ushort4*)(Y  + (size_t)g0 * DM))[threadIdx.x];
  const ushort4 a1 = ((const ushort4*)(Y1 + (size_t)g0 * DM))[threadIdx.x];
  const ushort4 b0 = ((const ushort4*)(Y  + (size_t)g1 * DM))[threadIdx.x];
  const ushort4 b1 = ((const ushort4*)(Y1 + (size_t)g1 * DM))[threadIdx.x];
  float4 o;
  o.x = w0 * (bf2f(a0.x) + bf2f(a1.x)) + w1 * (bf2f(b0.x) + bf2f(b1.x));
  o.y = w0 * (bf2f(a0.y) + bf2f(a1.y)) + w1 * (bf2f(b0.y) + bf2f(b1.y));
  o.z = w0 * (bf2f(a0.z) + bf2f(a1.z)) + w1 * (bf2f(b0.z) + bf2f(b1.z));
  o.w = w0 * (bf2f(a0.w) + bf2f(a1.w)) + w1 * (bf2f(b0.w) + bf2f(b1.w));
  ((float4*)(out + (size_t)tk * DM))[threadIdx.x] = o;
}

// ---------------------------------------------------------------------------
extern "C" void kernel_launch(void* const* d_in, const int* in_sizes, int n_in,
                              void* d_out, int out_size, void* d_ws, size_t ws_size,
                              hipStream_t stream) {
  const float* x    = (const float*)d_in[0];  // [2,2048,1024]
  const float* rw   = (const float*)d_in[1];  // [8,1024]
  const float* rb   = (const float*)d_in[2];  // [8]
  const float* W    = (const float*)d_in[3];  // [8,1024,2048]
  const float* V    = (const float*)d_in[4];  // [8,1024,2048]
  const float* Wout = (const float*)d_in[5];  // [8,2048,1024]
  float* out = (float*)d_out;

  // workspace carve-up (~145 MB); Y (bf16 [2][NSLOT][DM] = 32 MB) aliases
  // B1t (64 MB, dead after gemm1)
  char* p = (char*)d_ws;
  unsigned short* B1t = (unsigned short*)p; p += (size_t)NE * 4096 * DM * 2;   // 64 MB [e][n=4096][k=1024]
  unsigned short* Y   = (unsigned short*)B1t;                                  // alias: [2][NSLOT][DM] bf16
  unsigned short* B2t = (unsigned short*)p; p += (size_t)NE * DM * DH * 2;     // 32 MB [e][n=1024][k=2048]
  unsigned short* Xg  = (unsigned short*)p; p += (size_t)NSLOT * DM * 2;       // 16 MB
  unsigned short* G   = (unsigned short*)p; p += (size_t)NSLOT * DH * 2;       // 32 MB
  int*   counts      = (int*)p;   p += 256;
  int*   meta_e      = (int*)p;   p += (size_t)N_TOK * 2 * 4;
  int*   meta_idx    = (int*)p;   p += (size_t)N_TOK * 2 * 4;
  float* meta_p      = (float*)p; p += (size_t)N_TOK * 2 * 4;

  k_transpose<<<dim3(32, 16, 24), 256, 0, stream>>>(W, V, Wout, B1t, B2t, counts);
  k_router<<<N_TOK / 4, 256, 0, stream>>>(x, rw, rb, counts, meta_e, meta_idx, meta_p);
  k_gather<<<N_TOK, 256, 0, stream>>>(x, meta_e, meta_idx, counts, Xg);
  k_gemm1<<<dim3(DH / 128, NSLOT / 128, NE), 256, 0, stream>>>(Xg, B1t, G, counts);
  k_gemm2<<<dim3(DM / 128, NSLOT / 128, 2 * NE), 256, 0, stream>>>(G, B2t, Y, counts);
  k_combine<<<N_TOK, 256, 0, stream>>>(Y, meta_e, meta_idx, meta_p, counts, out);
}